// Round 1
// baseline (873.799 us; speedup 1.0000x reference)
//
#include <hip/hip_runtime.h>
#include <math.h>

#define Nn 15000
#define Ee 30000

// ---- workspace layout (float offsets) ----
#define OFF_OUT   0          // [Nn*64] node state (out == h)
#define OFF_AGG   960000     // [Nn*64] aggregated messages
#define OFF_DEG   1920000    // [Nn] degree
#define OFF_DINV  1935360    // [Nn] 1/max(deg,1)
#define OFF_ELOG  1950720    // [Nn] attention logits
#define OFF_A     1966080    // [65*4096] pattern A matrices
#define OFF_B     2232320    // [65*4096] pattern B matrices
#define OFF_BP    2498560    // [64] sorted breakpoints
#define OFF_U     2498624    // [65*64]
#define OFF_V     2502784    // [65*64]
#define OFF_MC    2506944    // [1 int] breakpoint count m
#define OFF_PE    2507008    // [Ee ints] per-edge pattern id
#define OFF_HS    2537024    // [64]
#define OFF_CS    2537088    // [64]
#define OFF_RV    2537152    // [64]
#define OFF_SM    2537216    // [2] softmax max, 1/Z
#define WS_FLOATS 2537280

__device__ __forceinline__ float sigf(float x) { return 1.0f / (1.0f + expf(-x)); }

// out[n,o] = relu(x[n,:3] @ lin0_w[o,:3] + lin0_b[o])
__global__ void k_lin0(const float* __restrict__ x, const float* __restrict__ w,
                       const float* __restrict__ b, float* __restrict__ out) {
    int idx = blockIdx.x * 256 + threadIdx.x;
    if (idx >= Nn * 64) return;
    int n = idx >> 6, o = idx & 63;
    float v = b[o] + x[n*3+0]*w[o*3+0] + x[n*3+1]*w[o*3+1] + x[n*3+2]*w[o*3+2];
    out[idx] = fmaxf(v, 0.0f);
}

__global__ void k_deg(const int* __restrict__ ei, float* __restrict__ deg) {
    int e = blockIdx.x * 256 + threadIdx.x;
    if (e >= Ee) return;
    atomicAdd(&deg[ei[Ee + e]], 1.0f);
}

__global__ void k_dinv(const float* __restrict__ deg, float* __restrict__ dinv) {
    int n = blockIdx.x * 256 + threadIdx.x;
    if (n >= Nn) return;
    dinv[n] = 1.0f / fmaxf(deg[n], 1.0f);
}

// he[e,k] = relu(a*w1[k]+b1[k]) is piecewise linear in scalar a with breakpoints
// -b1/w1 in (0,1). For pattern j (interval between sorted breakpoints) the relu
// mask is fixed: he = a*u_j + v_j exactly.
__global__ void k_patterns(const float* __restrict__ e1w, const float* __restrict__ e1b,
                           float* __restrict__ bp, float* __restrict__ u,
                           float* __restrict__ v, int* __restrict__ mc) {
    __shared__ float t[64]; __shared__ int valid[64]; __shared__ float sbp[65]; __shared__ int cnt;
    int k = threadIdx.x;
    float w1 = e1w[k], b1 = e1b[k];
    float tv = 0.f; int va = 0;
    if (w1 != 0.f) { tv = -b1 / w1; va = (tv > 0.f && tv < 1.f) ? 1 : 0; }
    t[k] = tv; valid[k] = va;
    __syncthreads();
    if (va) {
        int rank = 0;
        for (int kk = 0; kk < 64; ++kk)
            if (valid[kk] && (t[kk] < tv || (t[kk] == tv && kk < k))) rank++;
        sbp[rank] = tv;
    }
    if (k == 0) { int c = 0; for (int kk = 0; kk < 64; ++kk) c += valid[kk]; cnt = c; *mc = c; }
    __syncthreads();
    int m = cnt;
    if (k < m) bp[k] = sbp[k];
    for (int j = 0; j <= m; ++j) {
        float lo = (j == 0) ? 0.f : sbp[j-1];
        float hi = (j == m) ? 1.f : sbp[j];
        float c = 0.5f * (lo + hi);
        int msk = (c * w1 + b1) > 0.f;
        u[j*64 + k] = msk ? w1 : 0.f;
        v[j*64 + k] = msk ? b1 : 0.f;
    }
}

// A_j[q] = sum_k u_j[k]*e2w[q,k];  B_j[q] = sum_k v_j[k]*e2w[q,k] + e2b[q]
__global__ void k_AB(const float* __restrict__ e2w, const float* __restrict__ e2b,
                     const float* __restrict__ u, const float* __restrict__ v,
                     const int* __restrict__ mc, float* __restrict__ A, float* __restrict__ B) {
    int j = blockIdx.x;
    if (j > *mc) return;
    __shared__ float su[64], sv[64];
    if (threadIdx.x < 64) { su[threadIdx.x] = u[j*64+threadIdx.x]; sv[threadIdx.x] = v[j*64+threadIdx.x]; }
    __syncthreads();
    for (int q = threadIdx.x; q < 4096; q += 256) {
        const float* row = e2w + q*64;
        float a = 0.f, b = 0.f;
        #pragma unroll 8
        for (int k = 0; k < 64; ++k) { float w = row[k]; a = fmaf(su[k], w, a); b = fmaf(sv[k], w, b); }
        A[j*4096 + q] = a;
        B[j*4096 + q] = b + e2b[q];
    }
}

__global__ void k_classify(const float* __restrict__ ea, const float* __restrict__ bp,
                           const int* __restrict__ mc, int* __restrict__ pe) {
    int e = blockIdx.x * 256 + threadIdx.x;
    if (e >= Ee) return;
    float a = ea[e];
    int m = *mc;
    int p = 0;
    for (int j = 0; j < m; ++j) p += (bp[j] <= a) ? 1 : 0;
    pe[e] = p;
}

// one wave per edge: msg[o] = sum_i out[src,i]*(a*A_p[i,o]+B_p[i,o]); atomic into agg (pre-scaled by 1/deg)
__global__ void k_edge(const int* __restrict__ ei, const float* __restrict__ ea,
                       const int* __restrict__ pe, const float* __restrict__ out,
                       const float* __restrict__ A, const float* __restrict__ B,
                       const float* __restrict__ dinv, float* __restrict__ agg) {
    int gtid = blockIdx.x * 256 + threadIdx.x;
    int e = gtid >> 6;
    int lane = threadIdx.x & 63;
    if (e >= Ee) return;
    int src = ei[e], dst = ei[Ee + e];
    float a = ea[e];
    const float* Ap = A + pe[e] * 4096;
    const float* Bp = B + pe[e] * 4096;
    float ov = out[src*64 + lane];
    float acc = 0.f;
    #pragma unroll 8
    for (int i = 0; i < 64; ++i) {
        float oi = __shfl(ov, i, 64);
        acc = fmaf(oi, fmaf(a, Ap[i*64 + lane], Bp[i*64 + lane]), acc);
    }
    acc *= dinv[dst];
    atomicAdd(&agg[dst*64 + lane], acc);
}

// fused NNConv-root + GRU cell, one wave per node; weights LDS-cached
// (transposed, stride 193 to avoid bank conflicts). Re-zeros agg for next step.
__global__ __launch_bounds__(512) void k_gru(float* __restrict__ out, float* __restrict__ agg,
                      const float* __restrict__ rootw, const float* __restrict__ convb,
                      const float* __restrict__ wih, const float* __restrict__ whh,
                      const float* __restrict__ bih, const float* __restrict__ bhh) {
    __shared__ float s_root[4096];
    __shared__ float s_wih[12352];   // [i][j] 64 x 193 (192 used)
    __shared__ float s_whh[12352];
    __shared__ float s_bih[192], s_bhh[192], s_cb[64];
    int tid = threadIdx.x;
    for (int idx = tid; idx < 4096; idx += 512) s_root[idx] = rootw[idx];
    for (int idx = tid; idx < 12288; idx += 512) {
        int j = idx >> 6, i = idx & 63;
        s_wih[i*193 + j] = wih[idx];
        s_whh[i*193 + j] = whh[idx];
    }
    if (tid < 192) { s_bih[tid] = bih[tid]; s_bhh[tid] = bhh[tid]; }
    if (tid < 64) s_cb[tid] = convb[tid];
    __syncthreads();
    int lane = tid & 63;
    int wid = (blockIdx.x * 512 + tid) >> 6;
    int nw = gridDim.x * 8;
    for (int n = wid; n < Nn; n += nw) {
        float hv = out[n*64 + lane];
        float av = agg[n*64 + lane];
        float mo = s_cb[lane];
        #pragma unroll 16
        for (int i = 0; i < 64; ++i)
            mo = fmaf(__shfl(hv, i, 64), s_root[i*64 + lane], mo);
        float mv = fmaxf(av + mo, 0.f);
        float g0 = s_bih[lane], g1 = s_bih[lane+64], g2 = s_bih[lane+128];
        float h0 = s_bhh[lane], h1 = s_bhh[lane+64], h2 = s_bhh[lane+128];
        #pragma unroll 16
        for (int i = 0; i < 64; ++i) {
            float mb = __shfl(mv, i, 64);
            float hb = __shfl(hv, i, 64);
            const float* wr = s_wih + i*193;
            const float* hr = s_whh + i*193;
            g0 = fmaf(mb, wr[lane],     g0);
            g1 = fmaf(mb, wr[lane+64],  g1);
            g2 = fmaf(mb, wr[lane+128], g2);
            h0 = fmaf(hb, hr[lane],     h0);
            h1 = fmaf(hb, hr[lane+64],  h1);
            h2 = fmaf(hb, hr[lane+128], h2);
        }
        float r = sigf(g0 + h0);
        float z = sigf(g1 + h1);
        float nn = tanhf(fmaf(r, h2, g2));
        float hn = (1.f - z) * nn + z * hv;
        out[n*64 + lane] = hn;
        agg[n*64 + lane] = 0.f;   // ready for next conv step
    }
}

// Set2Set LSTM (1 block). Uses q_star = [hs, r] and x[0:64] == h == hs_prev.
__global__ void k_lstm(const float* __restrict__ wih, const float* __restrict__ whh,
                       const float* __restrict__ bih, const float* __restrict__ bhh,
                       float* __restrict__ hs, float* __restrict__ cs,
                       const float* __restrict__ rv) {
    __shared__ float shs[64], sr[64], sg[256];
    int tid = threadIdx.x;
    if (tid < 64) { shs[tid] = hs[tid]; sr[tid] = rv[tid]; }
    __syncthreads();
    {
        const float* wi = wih + tid*128;
        const float* wh = whh + tid*64;
        float g = bih[tid] + bhh[tid];
        #pragma unroll 8
        for (int i = 0; i < 64; ++i)
            g += shs[i]*(wi[i] + wh[i]) + sr[i]*wi[64+i];
        sg[tid] = g;
    }
    __syncthreads();
    if (tid < 64) {
        float ii = sigf(sg[tid]);
        float ff = sigf(sg[64+tid]);
        float gg = tanhf(sg[128+tid]);
        float oo = sigf(sg[192+tid]);
        float c2 = ff*cs[tid] + ii*gg;
        cs[tid] = c2;
        hs[tid] = oo*tanhf(c2);
    }
}

__global__ void k_logits(const float* __restrict__ out, const float* __restrict__ hs,
                         float* __restrict__ elog) {
    int tid = threadIdx.x;
    int wid = (blockIdx.x * 256 + tid) >> 6;
    int lane = tid & 63;
    if (wid >= Nn) return;
    float p = out[wid*64 + lane] * hs[lane];
    #pragma unroll
    for (int off = 32; off > 0; off >>= 1) p += __shfl_xor(p, off, 64);
    if (lane == 0) elog[wid] = p;
}

__global__ __launch_bounds__(1024) void k_prep(const float* __restrict__ elog,
                       float* __restrict__ sm, float* __restrict__ rv) {
    __shared__ float red[1024];
    int tid = threadIdx.x;
    float mx = -1e30f;
    for (int n = tid; n < Nn; n += 1024) mx = fmaxf(mx, elog[n]);
    red[tid] = mx; __syncthreads();
    for (int s = 512; s > 0; s >>= 1) {
        if (tid < s) red[tid] = fmaxf(red[tid], red[tid+s]);
        __syncthreads();
    }
    mx = red[0]; __syncthreads();
    float sum = 0.f;
    for (int n = tid; n < Nn; n += 1024) sum += expf(elog[n] - mx);
    red[tid] = sum; __syncthreads();
    for (int s = 512; s > 0; s >>= 1) {
        if (tid < s) red[tid] += red[tid+s];
        __syncthreads();
    }
    if (tid == 0) { sm[0] = mx; sm[1] = 1.0f / red[0]; }
    if (tid < 64) rv[tid] = 0.f;   // ready for k_attn accumulation
}

__global__ void k_attn(const float* __restrict__ out, const float* __restrict__ elog,
                       const float* __restrict__ sm, float* __restrict__ rv) {
    __shared__ float rbuf[4][64];
    int tid = threadIdx.x;
    int lane = tid & 63, w = tid >> 6;
    int wid = blockIdx.x * 4 + w;
    int nw = gridDim.x * 4;
    float mx = sm[0], iz = sm[1];
    float acc = 0.f;
    for (int n = wid; n < Nn; n += nw)
        acc = fmaf(expf(elog[n] - mx), out[n*64 + lane], acc);
    rbuf[w][lane] = acc;
    __syncthreads();
    if (tid < 64) {
        float s = (rbuf[0][tid] + rbuf[1][tid] + rbuf[2][tid] + rbuf[3][tid]) * iz;
        atomicAdd(&rv[tid], s);
    }
}

// mem-LSTM (h=c=0) + lin1 + lin3 -> d_out = [v, hx(64), cx(64)]
__global__ void k_final(const float* __restrict__ wih, const float* __restrict__ bih,
                        const float* __restrict__ bhh,
                        const float* __restrict__ hs, const float* __restrict__ rv,
                        const float* __restrict__ l1w, const float* __restrict__ l1b,
                        const float* __restrict__ l3w, const float* __restrict__ l3b,
                        float* __restrict__ dout) {
    __shared__ float shs[64], sr[64], sg[256], shx[64], so[64];
    int tid = threadIdx.x;
    if (tid < 64) { shs[tid] = hs[tid]; sr[tid] = rv[tid]; }
    __syncthreads();
    {
        const float* wi = wih + tid*128;
        float g = bih[tid] + bhh[tid];
        #pragma unroll 8
        for (int i = 0; i < 64; ++i)
            g += shs[i]*wi[i] + sr[i]*wi[64+i];
        sg[tid] = g;
    }
    __syncthreads();
    if (tid < 64) {
        float ii = sigf(sg[tid]);
        float gg = tanhf(sg[128+tid]);
        float oo = sigf(sg[192+tid]);
        float c2 = ii * gg;             // f*c0 = 0
        float hx = oo * tanhf(c2);
        shx[tid] = hx;
        dout[1 + tid] = hx;
        dout[65 + tid] = c2;
    }
    __syncthreads();
    if (tid < 64) {
        float a = l1b[tid];
        const float* wr = l1w + tid*64;
        #pragma unroll 8
        for (int i = 0; i < 64; ++i) a = fmaf(shx[i], wr[i], a);
        so[tid] = fmaxf(a, 0.f);
    }
    __syncthreads();
    if (tid == 0) {
        float v = l3b[0];
        for (int i = 0; i < 64; ++i) v = fmaf(so[i], l3w[i], v);
        dout[0] = v;
    }
}

extern "C" void kernel_launch(void* const* d_in, const int* in_sizes, int n_in,
                              void* d_out, int out_size, void* d_ws, size_t ws_size,
                              hipStream_t stream) {
    const float* x    = (const float*)d_in[0];
    const int*   ei   = (const int*)  d_in[1];
    const float* ea   = (const float*)d_in[2];
    const float* l0w  = (const float*)d_in[3];
    const float* l0b  = (const float*)d_in[4];
    const float* e1w  = (const float*)d_in[5];
    const float* e1b  = (const float*)d_in[6];
    const float* e2w  = (const float*)d_in[7];
    const float* e2b  = (const float*)d_in[8];
    const float* rootw= (const float*)d_in[9];
    const float* convb= (const float*)d_in[10];
    const float* gwih = (const float*)d_in[11];
    const float* gwhh = (const float*)d_in[12];
    const float* gbih = (const float*)d_in[13];
    const float* gbhh = (const float*)d_in[14];
    const float* swih = (const float*)d_in[15];
    const float* swhh = (const float*)d_in[16];
    const float* sbih = (const float*)d_in[17];
    const float* sbhh = (const float*)d_in[18];
    const float* mwih = (const float*)d_in[19];
    const float* mbih = (const float*)d_in[21];
    const float* mbhh = (const float*)d_in[22];
    const float* l1w  = (const float*)d_in[23];
    const float* l1b  = (const float*)d_in[24];
    const float* l3w  = (const float*)d_in[25];
    const float* l3b  = (const float*)d_in[26];

    float* ws   = (float*)d_ws;
    float* dout = (float*)d_out;
    if (ws_size < (size_t)WS_FLOATS * sizeof(float)) return;

    float* out  = ws + OFF_OUT;
    float* agg  = ws + OFF_AGG;
    float* deg  = ws + OFF_DEG;
    float* dinv = ws + OFF_DINV;
    float* elog = ws + OFF_ELOG;
    float* Abuf = ws + OFF_A;
    float* Bbuf = ws + OFF_B;
    float* bp   = ws + OFF_BP;
    float* ubuf = ws + OFF_U;
    float* vbuf = ws + OFF_V;
    int*   mc   = (int*)(ws + OFF_MC);
    int*   pe   = (int*)(ws + OFF_PE);
    float* hs   = ws + OFF_HS;
    float* cs   = ws + OFF_CS;
    float* rv   = ws + OFF_RV;
    float* sm   = ws + OFF_SM;

    hipMemsetAsync(d_ws, 0, (size_t)WS_FLOATS * sizeof(float), stream);

    k_lin0    <<<(Nn*64 + 255)/256, 256, 0, stream>>>(x, l0w, l0b, out);
    k_deg     <<<(Ee + 255)/256,    256, 0, stream>>>(ei, deg);
    k_dinv    <<<(Nn + 255)/256,    256, 0, stream>>>(deg, dinv);
    k_patterns<<<1, 64, 0, stream>>>(e1w, e1b, bp, ubuf, vbuf, mc);
    k_AB      <<<65, 256, 0, stream>>>(e2w, e2b, ubuf, vbuf, mc, Abuf, Bbuf);
    k_classify<<<(Ee + 255)/256,    256, 0, stream>>>(ea, bp, mc, pe);

    for (int s = 0; s < 6; ++s) {
        k_edge<<<(Ee*64 + 255)/256, 256, 0, stream>>>(ei, ea, pe, out, Abuf, Bbuf, dinv, agg);
        k_gru <<<256, 512, 0, stream>>>(out, agg, rootw, convb, gwih, gwhh, gbih, gbhh);
    }

    for (int it = 0; it < 6; ++it) {
        k_lstm  <<<1, 256, 0, stream>>>(swih, swhh, sbih, sbhh, hs, cs, rv);
        k_logits<<<(Nn + 3)/4, 256, 0, stream>>>(out, hs, elog);
        k_prep  <<<1, 1024, 0, stream>>>(elog, sm, rv);
        k_attn  <<<256, 256, 0, stream>>>(out, elog, sm, rv);
    }

    k_final<<<1, 256, 0, stream>>>(mwih, mbih, mbhh, hs, rv, l1w, l1b, l3w, l3b, dout);
}